// Round 2
// baseline (611.984 us; speedup 1.0000x reference)
//
#include <hip/hip_runtime.h>

#define B_ 1024
#define D_ 784
#define H_ 1024
#define BH_ (B_ * H_)
#define LOG2E 1.4426950408889634f

// Segment boundaries: {0, 200, 400, 592, 784} (multiples of 8 for prep chunks)

// ---------- prep: out[b*D + i] = bias[i] ----------
__global__ __launch_bounds__(256) void init_out_kernel(const float* __restrict__ bias,
                                                       float* __restrict__ out) {
    int i = blockIdx.x * 256 + threadIdx.x;
    if (i < D_) out[(size_t)blockIdx.y * D_ + i] = bias[i];
}

// ---------- prep: Wt[i*H + h] = W[h*D + i] * log2e ----------
__global__ __launch_bounds__(256) void transpose_scale_W(const float* __restrict__ W,
                                                         float* __restrict__ Wt) {
    __shared__ float t[32][33];
    int i0 = blockIdx.x * 32;               // D dim
    int h0 = blockIdx.y * 32;               // H dim
    int tx = threadIdx.x & 31, ty = threadIdx.x >> 5;   // 32 x 8
#pragma unroll
    for (int j = 0; j < 4; ++j) {
        int h = h0 + ty + j * 8;
        int i = i0 + tx;
        float v = 0.f;
        if (i < D_) v = W[(size_t)h * D_ + i] * LOG2E;
        t[ty + j * 8][tx] = v;
    }
    __syncthreads();
#pragma unroll
    for (int j = 0; j < 4; ++j) {
        int i = i0 + ty + j * 8;
        int h = h0 + tx;
        if (i < D_) Wt[(size_t)i * H_ + h] = t[tx][ty + j * 8];
    }
}

// ---------- prep: checkpoint accumulators via tiled prefix-GEMM ----------
// A0[s][b][h] = (c[h] + sum_{j < J_s} px[b][j] * W[h][j]) * log2e, J_s in {200,400,592}
__global__ __launch_bounds__(256) void prefix_gemm(const float* __restrict__ px,
                                                   const float* __restrict__ Wt,  // pre-scaled
                                                   const float* __restrict__ c,
                                                   float* __restrict__ A0) {
    __shared__ float xs[8][64];   // [j][b]
    __shared__ float ws[8][64];   // [j][h]
    const int t = threadIdx.x;
    const int b0 = blockIdx.x * 64, h0 = blockIdx.y * 64;
    const int tb = t >> 4, th = t & 15;     // 16x16 threads, each 4b x 4h

    float acc[4][4];
    float4 c4 = *(const float4*)(c + h0 + th * 4);
#pragma unroll
    for (int bi = 0; bi < 4; ++bi) {
        acc[bi][0] = c4.x * LOG2E; acc[bi][1] = c4.y * LOG2E;
        acc[bi][2] = c4.z * LOG2E; acc[bi][3] = c4.w * LOG2E;
    }
    const int xr = t >> 2, xc = (t & 3) * 2;

    for (int j0 = 0; j0 < 592; j0 += 8) {
        float2 xv = *(const float2*)(px + (size_t)(b0 + xr) * D_ + j0 + xc);
        float4 wv = make_float4(0, 0, 0, 0);
        if (t < 128) wv = *(const float4*)(Wt + (size_t)(j0 + (t >> 4)) * H_ + h0 + (t & 15) * 4);
        __syncthreads();
        xs[xc][xr] = xv.x; xs[xc + 1][xr] = xv.y;
        if (t < 128) *(float4*)&ws[t >> 4][(t & 15) * 4] = wv;
        __syncthreads();
#pragma unroll
        for (int jj = 0; jj < 8; ++jj) {
            float4 xb = *(float4*)&xs[jj][tb * 4];
            float4 wb = *(float4*)&ws[jj][th * 4];
            float xa[4] = {xb.x, xb.y, xb.z, xb.w};
            float wa[4] = {wb.x, wb.y, wb.z, wb.w};
#pragma unroll
            for (int bi = 0; bi < 4; ++bi)
#pragma unroll
                for (int hi = 0; hi < 4; ++hi)
                    acc[bi][hi] = fmaf(xa[bi], wa[hi], acc[bi][hi]);
        }
        int jend = j0 + 8;
        if (jend == 200 || jend == 400 || jend == 592) {
            int sidx = (jend == 200) ? 0 : (jend == 400) ? 1 : 2;
            float* dst = A0 + (size_t)sidx * BH_;
#pragma unroll
            for (int bi = 0; bi < 4; ++bi) {
                float4 o = make_float4(acc[bi][0], acc[bi][1], acc[bi][2], acc[bi][3]);
                *(float4*)(dst + (size_t)(b0 + tb * 4 + bi) * H_ + h0 + th * 4) = o;
            }
        }
    }
}

// ---------- DPP reduce: both 32-lane halves simultaneously ----------
template <int CTRL>
__device__ __forceinline__ float dpp_add(float p) {
    int s = __builtin_amdgcn_update_dpp(0, __float_as_int(p), CTRL, 0xf, 0xf, true);
    return p + __int_as_float(s);
}
__device__ __forceinline__ float reduce_halves(float p) {
    p = dpp_add<0x111>(p);
    p = dpp_add<0x112>(p);
    p = dpp_add<0x114>(p);
    p = dpp_add<0x118>(p);
    p = dpp_add<0x142>(p);   // lane31 = sum(0..31), lane63 = sum(32..63)
    return p;
}

// ---------- main NADE scan (4 D-segments, grouped rcp) ----------
__global__ __launch_bounds__(256, 8) void nade_main(
    const float* __restrict__ px,   // [B, D]
    const float* __restrict__ c,    // [H]
    const float* __restrict__ V,    // [D, H]
    const float* __restrict__ Wt,   // [D, H], pre-scaled by log2e
    const float* __restrict__ A0,   // [3][B][H] checkpoints (log2 domain)
    float* __restrict__ out)        // [B, D], pre-init to bias
{
    const int lane = threadIdx.x & 63;
    const int wid  = threadIdx.x >> 6;
    const int gw   = blockIdx.x * 4 + wid;   // 0..16383
    const int s    = gw & 3;
    const int r2   = gw >> 2;
    const int hb   = r2 & 7;
    const int rp   = r2 >> 3;                // 0..511
    const int half = lane >> 5;
    const int row  = rp * 2 + half;
    const int h0   = hb * 128 + (lane & 31) * 4;

    int i0, i1;
    if      (s == 0) { i0 = 0;   i1 = 200; }
    else if (s == 1) { i0 = 200; i1 = 400; }
    else if (s == 2) { i0 = 400; i1 = 592; }
    else             { i0 = 592; i1 = 784; }

    float A[4];
    if (s == 0) {
        float4 a4 = *(const float4*)(c + h0);
        A[0] = a4.x * LOG2E; A[1] = a4.y * LOG2E; A[2] = a4.z * LOG2E; A[3] = a4.w * LOG2E;
    } else {
        float4 a4 = *(const float4*)(A0 + (size_t)(s - 1) * BH_ + (size_t)row * H_ + h0);
        A[0] = a4.x; A[1] = a4.y; A[2] = a4.z; A[3] = a4.w;
    }

    const float* vp = V  + h0;
    const float* wp = Wt + h0;
    const float* xp = px + (size_t)row * D_;
    float*       op = out + (size_t)row * D_;

    float4 vv = *(const float4*)(vp + (size_t)i0 * H_);
    float4 ww = *(const float4*)(wp + (size_t)i0 * H_);
    float  x  = xp[i0];

    // one step: grouped reciprocal — p_lane = [q23(v0 q1 + v1 q0) + q01(v2 q3 + v3 q2)] * rcp(q0q1q2q3)
    auto step = [&](const float4& v4, const float4& w4, float xi) -> float {
        float e0 = __builtin_amdgcn_exp2f(fminf(30.f, -A[0]));
        float e1 = __builtin_amdgcn_exp2f(fminf(30.f, -A[1]));
        float e2 = __builtin_amdgcn_exp2f(fminf(30.f, -A[2]));
        float e3 = __builtin_amdgcn_exp2f(fminf(30.f, -A[3]));
        float q0 = 1.f + e0, q1 = 1.f + e1, q2 = 1.f + e2, q3 = 1.f + e3;
        float q01 = q0 * q1, q23 = q2 * q3;
        float r = __builtin_amdgcn_rcpf(q01 * q23);
        float t0 = v4.x * q1; t0 = fmaf(v4.y, q0, t0);
        float t1 = v4.z * q3; t1 = fmaf(v4.w, q2, t1);
        float n  = t0 * q23;  n  = fmaf(t1, q01, n);
        A[0] = fmaf(w4.x, xi, A[0]);
        A[1] = fmaf(w4.y, xi, A[1]);
        A[2] = fmaf(w4.z, xi, A[2]);
        A[3] = fmaf(w4.w, xi, A[3]);
        return n * r;
    };

    for (int i = i0; i < i1 - 1; ++i) {
        float4 vn = *(const float4*)(vp + (size_t)(i + 1) * H_);
        float4 wn = *(const float4*)(wp + (size_t)(i + 1) * H_);
        float  xn = xp[i + 1];

        float p = step(vv, ww, x);
        p = reduce_halves(p);
        if ((lane & 31) == 31) unsafeAtomicAdd(op + i, p);

        vv = vn; ww = wn; x = xn;
    }
    {
        float p = step(vv, ww, x);
        p = reduce_halves(p);
        if ((lane & 31) == 31) unsafeAtomicAdd(op + (i1 - 1), p);
    }
}

extern "C" void kernel_launch(void* const* d_in, const int* in_sizes, int n_in,
                              void* d_out, int out_size, void* d_ws, size_t ws_size,
                              hipStream_t stream) {
    const float* px   = (const float*)d_in[0];  // [B, D]
    const float* W    = (const float*)d_in[1];  // [H, D]
    const float* c    = (const float*)d_in[2];  // [H]
    const float* V    = (const float*)d_in[3];  // [D, H]
    const float* bias = (const float*)d_in[4];  // [D]
    float* out = (float*)d_out;                 // [B, D]

    float* Wt = (float*)d_ws;                   // [D, H]  (3.2 MB)
    float* A0 = Wt + (size_t)D_ * H_;           // [3][B][H] (12 MB)

    transpose_scale_W<<<dim3((D_ + 31) / 32, H_ / 32), 256, 0, stream>>>(W, Wt);
    init_out_kernel<<<dim3((D_ + 255) / 256, B_), 256, 0, stream>>>(bias, out);
    prefix_gemm<<<dim3(B_ / 64, H_ / 64), 256, 0, stream>>>(px, Wt, c, A0);

    // 4096 blocks x 4 waves = 16384 waves (4 segments x 4096)
    nade_main<<<dim3(4096), 256, 0, stream>>>(px, c, V, Wt, A0, out);
}

// Round 3
// 358.807 us; speedup vs baseline: 1.7056x; 1.7056x over previous
//
#include <hip/hip_runtime.h>

#define B_ 1024
#define D_ 784
#define H_ 1024
#define BH_ (B_ * H_)
#define LOG2E 1.4426950408889634f

// ws layout: Wt [D,H] (3.21 MB) | A0 [3][B][H] (12.6 MB) | part [8][B][D] (25.7 MB)

// ---------- prep: Wt[i*H + h] = W[h*D + i] * log2e ----------
__global__ __launch_bounds__(256) void transpose_scale_W(const float* __restrict__ W,
                                                         float* __restrict__ Wt) {
    __shared__ float t[32][33];
    int i0 = blockIdx.x * 32;               // D dim
    int h0 = blockIdx.y * 32;               // H dim
    int tx = threadIdx.x & 31, ty = threadIdx.x >> 5;   // 32 x 8
#pragma unroll
    for (int j = 0; j < 4; ++j) {
        int h = h0 + ty + j * 8;
        int i = i0 + tx;
        float v = 0.f;
        if (i < D_) v = W[(size_t)h * D_ + i] * LOG2E;
        t[ty + j * 8][tx] = v;
    }
    __syncthreads();
#pragma unroll
    for (int j = 0; j < 4; ++j) {
        int i = i0 + ty + j * 8;
        int h = h0 + tx;
        if (i < D_) Wt[(size_t)i * H_ + h] = t[tx][ty + j * 8];
    }
}

// ---------- prep: checkpoint accumulators via tiled prefix-GEMM ----------
// A0[s][b][h] = (c[h] + sum_{j < J_s} px[b][j] * W[h][j]) * log2e, J_s in {200,400,592}
__global__ __launch_bounds__(256) void prefix_gemm(const float* __restrict__ px,
                                                   const float* __restrict__ Wt,  // pre-scaled
                                                   const float* __restrict__ c,
                                                   float* __restrict__ A0) {
    __shared__ float xs[8][64];   // [j][b]
    __shared__ float ws[8][64];   // [j][h]
    const int t = threadIdx.x;
    const int b0 = blockIdx.x * 64, h0 = blockIdx.y * 64;
    const int tb = t >> 4, th = t & 15;     // 16x16 threads, each 4b x 4h

    float acc[4][4];
    float4 c4 = *(const float4*)(c + h0 + th * 4);
#pragma unroll
    for (int bi = 0; bi < 4; ++bi) {
        acc[bi][0] = c4.x * LOG2E; acc[bi][1] = c4.y * LOG2E;
        acc[bi][2] = c4.z * LOG2E; acc[bi][3] = c4.w * LOG2E;
    }
    const int xr = t >> 2, xc = (t & 3) * 2;

    for (int j0 = 0; j0 < 592; j0 += 8) {
        float2 xv = *(const float2*)(px + (size_t)(b0 + xr) * D_ + j0 + xc);
        float4 wv = make_float4(0, 0, 0, 0);
        if (t < 128) wv = *(const float4*)(Wt + (size_t)(j0 + (t >> 4)) * H_ + h0 + (t & 15) * 4);
        __syncthreads();
        xs[xc][xr] = xv.x; xs[xc + 1][xr] = xv.y;
        if (t < 128) *(float4*)&ws[t >> 4][(t & 15) * 4] = wv;
        __syncthreads();
#pragma unroll
        for (int jj = 0; jj < 8; ++jj) {
            float4 xb = *(float4*)&xs[jj][tb * 4];
            float4 wb = *(float4*)&ws[jj][th * 4];
            float xa[4] = {xb.x, xb.y, xb.z, xb.w};
            float wa[4] = {wb.x, wb.y, wb.z, wb.w};
#pragma unroll
            for (int bi = 0; bi < 4; ++bi)
#pragma unroll
                for (int hi = 0; hi < 4; ++hi)
                    acc[bi][hi] = fmaf(xa[bi], wa[hi], acc[bi][hi]);
        }
        int jend = j0 + 8;
        if (jend == 200 || jend == 400 || jend == 592) {
            int sidx = (jend == 200) ? 0 : (jend == 400) ? 1 : 2;
            float* dst = A0 + (size_t)sidx * BH_;
#pragma unroll
            for (int bi = 0; bi < 4; ++bi) {
                float4 o = make_float4(acc[bi][0], acc[bi][1], acc[bi][2], acc[bi][3]);
                *(float4*)(dst + (size_t)(b0 + tb * 4 + bi) * H_ + h0 + th * 4) = o;
            }
        }
    }
}

// ---------- DPP reduce: both 32-lane halves simultaneously ----------
template <int CTRL>
__device__ __forceinline__ float dpp_add(float p) {
    int s = __builtin_amdgcn_update_dpp(0, __float_as_int(p), CTRL, 0xf, 0xf, true);
    return p + __int_as_float(s);
}
__device__ __forceinline__ float reduce_halves(float p) {
    p = dpp_add<0x111>(p);
    p = dpp_add<0x112>(p);
    p = dpp_add<0x114>(p);
    p = dpp_add<0x118>(p);
    p = dpp_add<0x142>(p);   // lane31 = sum(0..31), lane63 = sum(32..63)
    return p;
}

// ---------- main NADE scan (4 D-segments, grouped rcp, NO atomics) ----------
__global__ __launch_bounds__(256, 8) void nade_main(
    const float* __restrict__ px,   // [B, D]
    const float* __restrict__ c,    // [H]
    const float* __restrict__ V,    // [D, H]
    const float* __restrict__ Wt,   // [D, H], pre-scaled by log2e
    const float* __restrict__ A0,   // [3][B][H] checkpoints (log2 domain)
    float* __restrict__ part)       // [8][B][D] private partials (one writer each)
{
    const int lane = threadIdx.x & 63;
    const int wid  = threadIdx.x >> 6;
    const int gw   = blockIdx.x * 4 + wid;   // 0..16383
    const int s    = gw & 3;
    const int r2   = gw >> 2;
    const int hb   = r2 & 7;
    const int rp   = r2 >> 3;                // 0..511
    const int half = lane >> 5;
    const int row  = rp * 2 + half;
    const int h0   = hb * 128 + (lane & 31) * 4;

    int i0, i1;
    if      (s == 0) { i0 = 0;   i1 = 200; }
    else if (s == 1) { i0 = 200; i1 = 400; }
    else if (s == 2) { i0 = 400; i1 = 592; }
    else             { i0 = 592; i1 = 784; }

    float A[4];
    if (s == 0) {
        float4 a4 = *(const float4*)(c + h0);
        A[0] = a4.x * LOG2E; A[1] = a4.y * LOG2E; A[2] = a4.z * LOG2E; A[3] = a4.w * LOG2E;
    } else {
        float4 a4 = *(const float4*)(A0 + (size_t)(s - 1) * BH_ + (size_t)row * H_ + h0);
        A[0] = a4.x; A[1] = a4.y; A[2] = a4.z; A[3] = a4.w;
    }

    const float* vp = V  + h0;
    const float* wp = Wt + h0;
    const float* xp = px + (size_t)row * D_;
    float*       pp = part + ((size_t)hb * B_ + row) * D_;

    // step: grouped reciprocal — p = [q23(v0 q1 + v1 q0) + q01(v2 q3 + v3 q2)] * rcp(q0q1q2q3)
    auto step = [&](const float4& v4, const float4& w4, float xi) -> float {
        float e0 = __builtin_amdgcn_exp2f(fminf(30.f, -A[0]));
        float e1 = __builtin_amdgcn_exp2f(fminf(30.f, -A[1]));
        float e2 = __builtin_amdgcn_exp2f(fminf(30.f, -A[2]));
        float e3 = __builtin_amdgcn_exp2f(fminf(30.f, -A[3]));
        float q0 = 1.f + e0, q1 = 1.f + e1, q2 = 1.f + e2, q3 = 1.f + e3;
        float q01 = q0 * q1, q23 = q2 * q3;
        float r = __builtin_amdgcn_rcpf(q01 * q23);
        float t0 = v4.x * q1; t0 = fmaf(v4.y, q0, t0);
        float t1 = v4.z * q3; t1 = fmaf(v4.w, q2, t1);
        float n  = t0 * q23;  n  = fmaf(t1, q01, n);
        A[0] = fmaf(w4.x, xi, A[0]);
        A[1] = fmaf(w4.y, xi, A[1]);
        A[2] = fmaf(w4.z, xi, A[2]);
        A[3] = fmaf(w4.w, xi, A[3]);
        return n * r;
    };

    float4 vv = *(const float4*)(vp + (size_t)i0 * H_);
    float4 ww = *(const float4*)(wp + (size_t)i0 * H_);
    float4 xq = *(const float4*)(xp + i0);      // i0 % 4 == 0, 16B-aligned

    for (int ib = i0; ib < i1; ib += 4) {       // segment lengths all % 4 == 0
        int xbn = (ib + 4 < i1) ? (ib + 4) : i0;
        float4 xq_n = *(const float4*)(xp + xbn);
        float xa[4] = {xq.x, xq.y, xq.z, xq.w};
#pragma unroll
        for (int j = 0; j < 4; ++j) {
            int i  = ib + j;
            int ip = (i + 1 < i1) ? (i + 1) : (i1 - 1);
            float4 vn = *(const float4*)(vp + (size_t)ip * H_);
            float4 wn = *(const float4*)(wp + (size_t)ip * H_);
            float p = step(vv, ww, xa[j]);
            p = reduce_halves(p);
            if ((lane & 31) == 31) pp[i] = p;   // plain store — no RMW, no contention
            vv = vn; ww = wn;
        }
        xq = xq_n;
    }
}

// ---------- epilogue: out[row][i] = bias[i] + sum_hb part[hb][row][i] ----------
__global__ __launch_bounds__(256) void reduce_out(const float* __restrict__ part,
                                                  const float* __restrict__ bias,
                                                  float* __restrict__ out) {
    int t = blockIdx.x * 256 + threadIdx.x;     // one thread per (row, 4-wide i chunk)
    if (t >= B_ * (D_ / 4)) return;
    int row = t / (D_ / 4);
    int ic  = (t - row * (D_ / 4)) * 4;
    float4 acc = *(const float4*)(bias + ic);
    const float* p = part + (size_t)row * D_ + ic;
#pragma unroll
    for (int hb = 0; hb < 8; ++hb) {
        float4 v = *(const float4*)(p + (size_t)hb * B_ * D_);
        acc.x += v.x; acc.y += v.y; acc.z += v.z; acc.w += v.w;
    }
    *(float4*)(out + (size_t)row * D_ + ic) = acc;
}

extern "C" void kernel_launch(void* const* d_in, const int* in_sizes, int n_in,
                              void* d_out, int out_size, void* d_ws, size_t ws_size,
                              hipStream_t stream) {
    const float* px   = (const float*)d_in[0];  // [B, D]
    const float* W    = (const float*)d_in[1];  // [H, D]
    const float* c    = (const float*)d_in[2];  // [H]
    const float* V    = (const float*)d_in[3];  // [D, H]
    const float* bias = (const float*)d_in[4];  // [D]
    float* out = (float*)d_out;                 // [B, D]

    float* Wt   = (float*)d_ws;                 // [D, H]
    float* A0   = Wt + (size_t)D_ * H_;         // [3][B][H]
    float* part = A0 + (size_t)3 * BH_;         // [8][B][D]

    transpose_scale_W<<<dim3((D_ + 31) / 32, H_ / 32), 256, 0, stream>>>(W, Wt);
    prefix_gemm<<<dim3(B_ / 64, H_ / 64), 256, 0, stream>>>(px, Wt, c, A0);

    nade_main<<<dim3(4096), 256, 0, stream>>>(px, c, V, Wt, A0, part);

    reduce_out<<<dim3((B_ * (D_ / 4) + 255) / 256), 256, 0, stream>>>(part, bias, out);
}

// Round 4
// 347.983 us; speedup vs baseline: 1.7587x; 1.0311x over previous
//
#include <hip/hip_runtime.h>

#define B_ 1024
#define D_ 784
#define H_ 1024
#define BH_ (B_ * H_)
#define LOG2E 1.4426950408889634f

// ws layout: VW [D][4][512] (V 256 fp32 | W*log2e 256 fp32) 6.42 MB
//          | A0 [3][B][H] 12.6 MB | part [4][B][D] 12.8 MB

// ---------- prep: build interleaved VW (V copy + W transpose*log2e) ----------
__global__ __launch_bounds__(256) void build_vw(const float* __restrict__ V,
                                                const float* __restrict__ W,
                                                float* __restrict__ VW) {
    __shared__ float t[32][33];
    int i0 = blockIdx.x * 32;   // D dim
    int h0 = blockIdx.y * 32;   // H dim
    int tx = threadIdx.x & 31, ty = threadIdx.x >> 5;   // 32 x 8
    int hb = h0 >> 8, hl = h0 & 255;
    // V copy (coalesced both sides)
#pragma unroll
    for (int j = 0; j < 4; ++j) {
        int i = i0 + ty + j * 8;
        if (i < D_)
            VW[((size_t)i * 4 + hb) * 512 + hl + tx] = V[(size_t)i * H_ + h0 + tx];
    }
    // W transpose via LDS, scaled by log2e
#pragma unroll
    for (int j = 0; j < 4; ++j) {
        int h = h0 + ty + j * 8;
        int i = i0 + tx;
        float v = 0.f;
        if (i < D_) v = W[(size_t)h * D_ + i] * LOG2E;
        t[ty + j * 8][tx] = v;
    }
    __syncthreads();
#pragma unroll
    for (int j = 0; j < 4; ++j) {
        int i = i0 + ty + j * 8;
        if (i < D_)
            VW[((size_t)i * 4 + hb) * 512 + 256 + hl + tx] = t[tx][ty + j * 8];
    }
}

// ---------- prep: checkpoints A0[s][b][h] = (c + px[:, :J_s] W[:, :J_s]^T) * log2e ----------
// J_s in {200, 400, 592}; reads the W half of VW (already *log2e)
__global__ __launch_bounds__(256) void prefix_gemm(const float* __restrict__ px,
                                                   const float* __restrict__ VW,
                                                   const float* __restrict__ c,
                                                   float* __restrict__ A0) {
    __shared__ float xs[8][64];   // [j][b]
    __shared__ float ws[8][64];   // [j][h]
    const int t = threadIdx.x;
    const int b0 = blockIdx.x * 64, h0 = blockIdx.y * 64;
    const int hbg = h0 >> 8, hlg = h0 & 255;
    const int tb = t >> 4, th = t & 15;     // 16x16 threads, each 4b x 4h

    float acc[4][4];
    float4 c4 = *(const float4*)(c + h0 + th * 4);
#pragma unroll
    for (int bi = 0; bi < 4; ++bi) {
        acc[bi][0] = c4.x * LOG2E; acc[bi][1] = c4.y * LOG2E;
        acc[bi][2] = c4.z * LOG2E; acc[bi][3] = c4.w * LOG2E;
    }
    const int xr = t >> 2, xc = (t & 3) * 2;

    for (int j0 = 0; j0 < 592; j0 += 8) {
        float2 xv = *(const float2*)(px + (size_t)(b0 + xr) * D_ + j0 + xc);
        float4 wv = make_float4(0, 0, 0, 0);
        if (t < 128)
            wv = *(const float4*)(VW + ((size_t)(j0 + (t >> 4)) * 4 + hbg) * 512 + 256 + hlg + (t & 15) * 4);
        __syncthreads();
        xs[xc][xr] = xv.x; xs[xc + 1][xr] = xv.y;
        if (t < 128) *(float4*)&ws[t >> 4][(t & 15) * 4] = wv;
        __syncthreads();
#pragma unroll
        for (int jj = 0; jj < 8; ++jj) {
            float4 xb = *(float4*)&xs[jj][tb * 4];
            float4 wb = *(float4*)&ws[jj][th * 4];
            float xa[4] = {xb.x, xb.y, xb.z, xb.w};
            float wa[4] = {wb.x, wb.y, wb.z, wb.w};
#pragma unroll
            for (int bi = 0; bi < 4; ++bi)
#pragma unroll
                for (int hi = 0; hi < 4; ++hi)
                    acc[bi][hi] = fmaf(xa[bi], wa[hi], acc[bi][hi]);
        }
        int jend = j0 + 8;
        if (jend == 200 || jend == 400 || jend == 592) {
            int sidx = (jend == 200) ? 0 : (jend == 400) ? 1 : 2;
            float* dst = A0 + (size_t)sidx * BH_;
#pragma unroll
            for (int bi = 0; bi < 4; ++bi) {
                float4 o = make_float4(acc[bi][0], acc[bi][1], acc[bi][2], acc[bi][3]);
                *(float4*)(dst + (size_t)(b0 + tb * 4 + bi) * H_ + h0 + th * 4) = o;
            }
        }
    }
}

// ---------- DPP reduce: both 32-lane halves simultaneously ----------
template <int CTRL>
__device__ __forceinline__ float dpp_add(float p) {
    int s = __builtin_amdgcn_update_dpp(0, __float_as_int(p), CTRL, 0xf, 0xf, true);
    return p + __int_as_float(s);
}
__device__ __forceinline__ float reduce_halves(float p) {
    p = dpp_add<0x111>(p);
    p = dpp_add<0x112>(p);
    p = dpp_add<0x114>(p);
    p = dpp_add<0x118>(p);
    p = dpp_add<0x142>(p);   // lane31 = sum(0..31), lane63 = sum(32..63)
    return p;
}

// ---------- main NADE scan: 4 D-segments x 4 h-blocks, 8 h/lane ----------
__global__ __launch_bounds__(256, 8) void nade_main(
    const float* __restrict__ px,   // [B, D]
    const float* __restrict__ c,    // [H]
    const float* __restrict__ VW,   // [D][4][512] interleaved
    const float* __restrict__ A0,   // [3][B][H] checkpoints (log2 domain)
    float* __restrict__ part)       // [4][B][D] private partials
{
    const int lane = threadIdx.x & 63;
    const int wid  = threadIdx.x >> 6;
    const int gw   = blockIdx.x * 4 + wid;   // 0..8191
    const int s    = gw & 3;
    const int hb   = (gw >> 2) & 3;
    const int rp   = gw >> 4;                // 0..511
    const int half = lane >> 5;
    const int row  = rp * 2 + half;
    const int hl   = lane & 31;
    const int h0   = hb * 256 + hl * 8;

    int i0s, i1s;
    if      (s == 0) { i0s = 0;   i1s = 200; }
    else if (s == 1) { i0s = 200; i1s = 400; }
    else if (s == 2) { i0s = 400; i1s = 592; }
    else             { i0s = 592; i1s = 784; }

    float A[8];
    if (s == 0) {
        float4 a0 = *(const float4*)(c + h0);
        float4 a1 = *(const float4*)(c + h0 + 4);
        A[0] = a0.x * LOG2E; A[1] = a0.y * LOG2E; A[2] = a0.z * LOG2E; A[3] = a0.w * LOG2E;
        A[4] = a1.x * LOG2E; A[5] = a1.y * LOG2E; A[6] = a1.z * LOG2E; A[7] = a1.w * LOG2E;
    } else {
        const float* ap = A0 + (size_t)(s - 1) * BH_ + (size_t)row * H_ + h0;
        float4 a0 = *(const float4*)(ap);
        float4 a1 = *(const float4*)(ap + 4);
        A[0] = a0.x; A[1] = a0.y; A[2] = a0.z; A[3] = a0.w;
        A[4] = a1.x; A[5] = a1.y; A[6] = a1.z; A[7] = a1.w;
    }

    const float* xp = px + (size_t)row * D_;
    float*       pp = part + ((size_t)hb * B_ + row) * D_;
    const float* vw = VW + ((size_t)i0s * 4 + hb) * 512 + hl * 8;

    // grouped reciprocal over 4 q's: p = [q23(v0 q1 + v1 q0) + q01(v2 q3 + v3 q2)] * rcp(q0q1q2q3)
    auto grp4 = [&A](const float4& v4, const float4& w4, float xi, int k0) -> float {
        float e0 = __builtin_amdgcn_exp2f(fminf(30.f, -A[k0 + 0]));
        float e1 = __builtin_amdgcn_exp2f(fminf(30.f, -A[k0 + 1]));
        float e2 = __builtin_amdgcn_exp2f(fminf(30.f, -A[k0 + 2]));
        float e3 = __builtin_amdgcn_exp2f(fminf(30.f, -A[k0 + 3]));
        float q0 = 1.f + e0, q1 = 1.f + e1, q2 = 1.f + e2, q3 = 1.f + e3;
        float q01 = q0 * q1, q23 = q2 * q3;
        float r = __builtin_amdgcn_rcpf(q01 * q23);
        float t0 = v4.x * q1; t0 = fmaf(v4.y, q0, t0);
        float t1 = v4.z * q3; t1 = fmaf(v4.w, q2, t1);
        float n  = t0 * q23;  n  = fmaf(t1, q01, n);
        A[k0 + 0] = fmaf(w4.x, xi, A[k0 + 0]);
        A[k0 + 1] = fmaf(w4.y, xi, A[k0 + 1]);
        A[k0 + 2] = fmaf(w4.z, xi, A[k0 + 2]);
        A[k0 + 3] = fmaf(w4.w, xi, A[k0 + 3]);
        return n * r;
    };

    for (int ib = i0s; ib < i1s; ib += 4) {     // all segment lengths % 4 == 0
        float4 xq = *(const float4*)(xp + ib);
        float xa[4] = {xq.x, xq.y, xq.z, xq.w};
        float pr[4];
#pragma unroll
        for (int j = 0; j < 4; ++j) {
            float4 v0 = *(const float4*)(vw + 0);
            float4 v1 = *(const float4*)(vw + 4);
            float4 w0 = *(const float4*)(vw + 256);
            float4 w1 = *(const float4*)(vw + 260);
            float p = grp4(v0, w0, xa[j], 0) + grp4(v1, w1, xa[j], 4);
            pr[j] = reduce_halves(p);
            vw += 2048;
        }
        if (hl == 31) {
            float4 o = make_float4(pr[0], pr[1], pr[2], pr[3]);
            *(float4*)(pp + ib) = o;            // plain vector store, one per 4 steps
        }
    }
}

// ---------- epilogue: out[row][i] = bias[i] + sum_hb part[hb][row][i] ----------
__global__ __launch_bounds__(256) void reduce_out(const float* __restrict__ part,
                                                  const float* __restrict__ bias,
                                                  float* __restrict__ out) {
    int t = blockIdx.x * 256 + threadIdx.x;     // one thread per (row, 4-wide i chunk)
    if (t >= B_ * (D_ / 4)) return;
    int row = t / (D_ / 4);
    int ic  = (t - row * (D_ / 4)) * 4;
    float4 acc = *(const float4*)(bias + ic);
    const float* p = part + (size_t)row * D_ + ic;
#pragma unroll
    for (int hb = 0; hb < 4; ++hb) {
        float4 v = *(const float4*)(p + (size_t)hb * B_ * D_);
        acc.x += v.x; acc.y += v.y; acc.z += v.z; acc.w += v.w;
    }
    *(float4*)(out + (size_t)row * D_ + ic) = acc;
}

extern "C" void kernel_launch(void* const* d_in, const int* in_sizes, int n_in,
                              void* d_out, int out_size, void* d_ws, size_t ws_size,
                              hipStream_t stream) {
    const float* px   = (const float*)d_in[0];  // [B, D]
    const float* W    = (const float*)d_in[1];  // [H, D]
    const float* c    = (const float*)d_in[2];  // [H]
    const float* V    = (const float*)d_in[3];  // [D, H]
    const float* bias = (const float*)d_in[4];  // [D]
    float* out = (float*)d_out;                 // [B, D]

    float* VW   = (float*)d_ws;                 // [D][4][512]
    float* A0   = VW + (size_t)D_ * 2048;       // [3][B][H]
    float* part = A0 + (size_t)3 * BH_;         // [4][B][D]

    build_vw<<<dim3((D_ + 31) / 32, H_ / 32), 256, 0, stream>>>(V, W, VW);
    prefix_gemm<<<dim3(B_ / 64, H_ / 64), 256, 0, stream>>>(px, VW, c, A0);

    // 2048 blocks x 4 waves = 8192 waves = exactly 8 waves/SIMD, one residency round
    nade_main<<<dim3(2048), 256, 0, stream>>>(px, c, VW, A0, part);

    reduce_out<<<dim3((B_ * (D_ / 4) + 255) / 256), 256, 0, stream>>>(part, bias, out);
}